// Round 6
// baseline (435.835 us; speedup 1.0000x reference)
//
#include <hip/hip_runtime.h>
#include <stdint.h>

#define TEMP      0.07f
#define BATCH     256
#define NROWS     32768
#define DIM       2048
#define KNEG      8192

typedef __attribute__((ext_vector_type(8))) short bf16x8;
typedef __attribute__((ext_vector_type(4))) float f32x4;

// ---------------------------------------------------------------- threefry2x32
__host__ __device__ inline void tf2x32(uint32_t ka, uint32_t kb,
                                       uint32_t x0, uint32_t x1,
                                       uint32_t& o0, uint32_t& o1) {
  uint32_t ks2 = ka ^ kb ^ 0x1BD11BDAu;
#define TFR(r) { x0 += x1; x1 = (x1 << r) | (x1 >> (32 - r)); x1 ^= x0; }
  x0 += ka; x1 += kb;
  TFR(13) TFR(15) TFR(26) TFR(6)
  x0 += kb;  x1 += ks2 + 1u;
  TFR(17) TFR(29) TFR(16) TFR(24)
  x0 += ks2; x1 += ka + 2u;
  TFR(13) TFR(15) TFR(26) TFR(6)
  x0 += ka;  x1 += kb + 3u;
  TFR(17) TFR(29) TFR(16) TFR(24)
  x0 += kb;  x1 += ks2 + 4u;
  TFR(13) TFR(15) TFR(26) TFR(6)
  x0 += ks2; x1 += ka + 5u;
#undef TFR
  o0 = x0; o1 = x1;
}

// partitionable threefry (JAX >= 0.4.36): bits = out0 ^ out1, counter = (0, q)
__device__ inline uint32_t ubits_at(uint32_t ka, uint32_t kb, uint32_t q) {
  uint32_t a, b; tf2x32(ka, kb, 0u, q, a, b);
  return (a ^ b) >> 9;
}

// ---------------------------------------------------------------- block reduce
__device__ inline float block_sum(float v, float* sm) {
  __syncthreads();
  const int lane = threadIdx.x & 63;
  const int w = threadIdx.x >> 6;
  const int nw = blockDim.x >> 6;
  for (int o = 32; o; o >>= 1) v += __shfl_down(v, o, 64);
  if (lane == 0) sm[w] = v;
  __syncthreads();
  if (w == 0) {
    float x = (lane < nw) ? sm[lane] : 0.f;
    for (int o = 8; o; o >>= 1) x += __shfl_down(x, o, 64);
    if (lane == 0) sm[0] = x;
  }
  __syncthreads();
  return sm[0];
}

__device__ inline uint32_t pk2(float a, float b) {  // 2x fp32 -> packed bf16 (RNE)
  uint32_t ua = __float_as_uint(a), ub = __float_as_uint(b);
  ua = (ua + 0x7FFFu + ((ua >> 16) & 1u)) >> 16;
  ub = (ub + 0x7FFFu + ((ub >> 16) & 1u)) >> 16;
  return ua | (ub << 16);
}

// -------------------------- pack f_nv into bf16 MFMA A-fragment layout (1 MB)
// Fragment tile (mt,kt): 1 KB, lane l holds rows mt*16+(l&15), k kt*32+(l>>4)*8.
__global__ __launch_bounds__(256) void cvtA(const float* __restrict__ A,
                                            uint32_t* __restrict__ Abf) {
  const int t = threadIdx.x;
  const int w = blockIdx.x * 4 + (t >> 6);   // 1024 fragment tiles
  const int l = t & 63;
  const int mt = w >> 6, kt = w & 63;
  const float* src = &A[(size_t)(mt * 16 + (l & 15)) * DIM + kt * 32 + (l >> 4) * 8];
  float4 f0 = *(const float4*)src;
  float4 f1 = *(const float4*)(src + 4);
  *(uint4*)(Abf + (size_t)w * 256 + l * 4) =
      make_uint4(pk2(f0.x, f0.y), pk2(f0.z, f0.w), pk2(f1.x, f1.y), pk2(f1.z, f1.w));
}

// ---------------------- fragment-direct GEMM + fused features->out copy
// No LDS, no barriers: features rows ARE the MFMA B-fragments (16B/lane
// contiguous in a row-major [N][K] matrix). Per wave: 128x16 output tile,
// acc[8], B-stream 2-deep register prefetch (4-buffer static rotation).
// 1024 blocks x 256 thr -> 4 blocks/CU, 16 waves/CU, pure dataflow.
__global__ __launch_bounds__(256, 4) void gemm_direct(
    const uint32_t* __restrict__ Abf,  // packed f_nv bf16 A-fragments
    const float* __restrict__ Bfeat,   // features [32768][2048]
    float* __restrict__ C,             // mat_sim [256][32768]
    float* __restrict__ outF,          // out+1 (new_features)
    int skip) {                        // copy only feature rows >= skip
  const int t = threadIdx.x;
  const int l = t & 63, w = t >> 6;
  const int mh = w & 1;                // m-half: rows mh*128..+128
  const int n0 = blockIdx.x * 32 + (w >> 1) * 16;
  const int row = n0 + (l & 15);       // feature row this lane streams
  const int kg = (l >> 4) * 8;         // k-offset within a 32-wide K-step
  const float* bsrc = &Bfeat[(size_t)row * DIM + kg];
  float* bdst = &outF[(size_t)row * DIM + kg];
  const bool do_copy = (mh == 0) && (row >= skip);
  const int mh8 = mh * 8;

  f32x4 acc[8] = {};
  f32x4 b0a, b0b, b1a, b1b, b2a, b2b, b3a, b3b;

#define BLOAD(LA, LB, KS) {                                                  \
    LA = *(const f32x4*)(bsrc + (KS) * 32);                                  \
    LB = *(const f32x4*)(bsrc + (KS) * 32 + 4); }

#define AFRAGP(MT, KS) \
  (*(const bf16x8*)(Abf + (size_t)((MT) * 64 + (KS)) * 256 + l * 4))

#define STEP(CA, CB, LA, LB, KS) {                                           \
    if ((KS) + 2 < DIM / 32) { BLOAD(LA, LB, (KS) + 2); }                    \
    uint32_t cw0, cw1, cw2, cw3;                                             \
    asm("v_cvt_pk_bf16_f32 %0, %1, %2" : "=v"(cw0) : "v"(CA[0]), "v"(CA[1]));\
    asm("v_cvt_pk_bf16_f32 %0, %1, %2" : "=v"(cw1) : "v"(CA[2]), "v"(CA[3]));\
    asm("v_cvt_pk_bf16_f32 %0, %1, %2" : "=v"(cw2) : "v"(CB[0]), "v"(CB[1]));\
    asm("v_cvt_pk_bf16_f32 %0, %1, %2" : "=v"(cw3) : "v"(CB[2]), "v"(CB[3]));\
    union { uint32_t u[4]; bf16x8 v; } bf_;                                  \
    bf_.u[0] = cw0; bf_.u[1] = cw1; bf_.u[2] = cw2; bf_.u[3] = cw3;          \
    if (do_copy) {                                                           \
      __builtin_nontemporal_store(CA, (f32x4*)(bdst + (KS) * 32));           \
      __builtin_nontemporal_store(CB, (f32x4*)(bdst + (KS) * 32 + 4));       \
    }                                                                        \
    _Pragma("unroll")                                                        \
    for (int m_ = 0; m_ < 8; ++m_)                                           \
      acc[m_] = __builtin_amdgcn_mfma_f32_16x16x32_bf16(                     \
          AFRAGP(mh8 + m_, KS), bf_.v, acc[m_], 0, 0, 0);                    \
  }

  BLOAD(b0a, b0b, 0);
  BLOAD(b1a, b1b, 1);
  for (int ks = 0; ks < DIM / 32; ks += 4) {
    STEP(b0a, b0b, b2a, b2b, ks);
    STEP(b1a, b1b, b3a, b3b, ks + 1);
    STEP(b2a, b2b, b0a, b0b, ks + 2);
    STEP(b3a, b3b, b1a, b1b, ks + 3);
  }

  // C write: lane holds C[(l>>4)*4 + r][l&15] of each 16x16 tile
#pragma unroll
  for (int m = 0; m < 8; ++m) {
    size_t base = (size_t)(mh * 128 + m * 16 + (l >> 4) * 4) * NROWS + n0 + (l & 15);
#pragma unroll
    for (int r = 0; r < 4; ++r)
      C[base + (size_t)r * NROWS] = acc[m][r];
  }
#undef BLOAD
#undef AFRAGP
#undef STEP
}

// -------------------------------------------------- per-row sampling + CE loss
__global__ __launch_bounds__(1024) void sample_loss(
    const float* __restrict__ f, const float* __restrict__ f_nv,
    const float* __restrict__ features, const int* __restrict__ labels,
    const int* __restrict__ indexes, const float* __restrict__ mat_sim,
    float* __restrict__ row_loss,
    uint32_t k1a, uint32_t k1b, uint32_t k2a, uint32_t k2b,
    uint32_t k3a, uint32_t k3b) {
  __shared__ uint32_t keys[NROWS];      // 128 KiB sortable uniform bits
  __shared__ uint32_t hist4[4][256];    // privatized histograms
  __shared__ uint32_t hist[256];
  __shared__ unsigned long long am1, am2;
  __shared__ int tie_j[128];
  __shared__ int tie_cnt;
  __shared__ float sred[16];
  __shared__ float swm[16], sws[16];
  __shared__ uint32_t bc_prefix, bc_rem;
  __shared__ int blab_s;

  const int t = threadIdx.x;
  const int i = blockIdx.x;
  const size_t mbase = (size_t)i * NROWS;

  if (t == 0) {
    blab_s = labels[indexes[i]];
    am1 = 0ull; am2 = 0ull; tie_cnt = 0;
  }
  ((uint32_t*)hist4)[t] = 0u;           // pass-0 histogram built during phase 1
  __syncthreads();
  const int blab = blab_s;
  const int hsel = t >> 8;

  // phase 1: keys for g3 (positives -> 0), argmax of g1/g2 over positives,
  // fused radix pass-0 histogram (bucket = key >> 15)
#pragma unroll 2
  for (int s = 0; s < NROWS / 1024; ++s) {
    int j = t + 1024 * s;
    uint32_t q = (uint32_t)i * NROWS + (uint32_t)j;
    int lab = labels[j];
    uint32_t key;
    if (lab == blab) {
      key = 0u;
      unsigned long long lo = (unsigned long long)(uint32_t)(NROWS - 1 - j);
      uint32_t u1 = ubits_at(k1a, k1b, q);
      uint32_t u2 = ubits_at(k2a, k2b, q);
      atomicMax(&am1, ((unsigned long long)u1 << 32) | lo);
      atomicMax(&am2, ((unsigned long long)u2 << 32) | lo);
    } else {
      key = ubits_at(k3a, k3b, q);
    }
    keys[j] = key;
    atomicAdd(&hist4[hsel][key >> 15], 1u);
  }
  __syncthreads();

  const int jw = NROWS - 1 - (int)(unsigned)(am1 & 0xFFFFFFFFull);
  const int jp = NROWS - 1 - (int)(unsigned)(am2 & 0xFFFFFFFFull);

  const int bank = indexes[i];
  float d1 = 0.f, d2 = 0.f, d3 = 0.f;
  for (int d = t; d < DIM; d += 1024) {
    float fnv = f_nv[(size_t)i * DIM + d];
    d1 += fnv * features[(size_t)bank * DIM + d];
    d2 += f[(size_t)i * DIM + d] * features[(size_t)jw * DIM + d];
    d3 += fnv * features[(size_t)jp * DIM + d];
  }
  const float l_pos = block_sum(d1, sred);
  const float posw  = block_sum(d2, sred);
  const float posv  = block_sum(d3, sred);

  // 3-pass radix select (pass 0 pre-built): K-th largest of 23-bit keys
  uint32_t prefix = 0, remaining = KNEG;
  const int shifts[3] = {15, 7, 0};
  const int nbits[3]  = {8, 8, 7};
  for (int p = 0; p < 3; ++p) {
    const int sh = shifts[p];
    const int nb = 1 << nbits[p];
    if (p) {
      ((uint32_t*)hist4)[t] = 0u;
      __syncthreads();
      for (int s = 0; s < NROWS / 1024; ++s) {
        int j = t + 1024 * s;
        uint32_t k = keys[j];
        if ((k >> (sh + nbits[p])) == prefix)
          atomicAdd(&hist4[hsel][(k >> sh) & (uint32_t)(nb - 1)], 1u);
      }
    }
    __syncthreads();
    if (t < nb) hist[t] = hist4[0][t] + hist4[1][t] + hist4[2][t] + hist4[3][t];
    __syncthreads();
    if (t == 0) {
      uint32_t c = 0; int b = nb - 1;
      for (;; --b) {
        c += hist[b];
        if (c >= remaining || b == 0) break;
      }
      bc_prefix = (prefix << nbits[p]) | (uint32_t)b;
      bc_rem = remaining - (c - hist[b]);
    }
    __syncthreads();
    prefix = bc_prefix; remaining = bc_rem;
  }
  const uint32_t T = prefix;
  const uint32_t need = remaining;

  float m = -INFINITY, ssum = 0.f;
  for (int s = 0; s < NROWS / 1024; ++s) {
    int j = t + 1024 * s;
    uint32_t k = keys[j];
    if (k > T) {
      float v = mat_sim[mbase + j] / TEMP;
      if (v <= m) ssum += expf(v - m);
      else { ssum = ssum * expf(m - v) + 1.0f; m = v; }
    } else if (k == T) {
      int p = atomicAdd(&tie_cnt, 1);
      if (p < 128) tie_j[p] = j;
    }
  }
  for (int o = 32; o; o >>= 1) {
    float m2 = __shfl_down(m, o, 64);
    float s2 = __shfl_down(ssum, o, 64);
    if (m2 > m) { ssum = ssum * expf(m - m2) + s2; m = m2; }
    else if (m2 != -INFINITY) ssum += s2 * expf(m2 - m);
  }
  if ((t & 63) == 0) { swm[t >> 6] = m; sws[t >> 6] = ssum; }
  __syncthreads();
  if (t < 64) {
    float mm = (t < 16) ? swm[t] : -INFINITY;
    float ss = (t < 16) ? sws[t] : 0.f;
    for (int o = 8; o; o >>= 1) {
      float m2 = __shfl_down(mm, o, 64);
      float s2 = __shfl_down(ss, o, 64);
      if (m2 > mm) { ss = ss * expf(mm - m2) + s2; mm = m2; }
      else if (m2 != -INFINITY) ss += s2 * expf(m2 - mm);
    }
    if (t == 0) { swm[0] = mm; sws[0] = ss; }
  }
  __syncthreads();

  if (t == 0) {
    float M = swm[0], S = sws[0];
    int tc = tie_cnt;
    if (tc <= 128) {
      for (int a2 = 1; a2 < tc; ++a2) {
        int v = tie_j[a2]; int b2 = a2 - 1;
        while (b2 >= 0 && tie_j[b2] > v) { tie_j[b2 + 1] = tie_j[b2]; --b2; }
        tie_j[b2 + 1] = v;
      }
      for (uint32_t r = 0; r < need; ++r) {
        float v = mat_sim[mbase + tie_j[r]] / TEMP;
        if (v <= M) S += expf(v - M);
        else { S = S * expf(M - v) + 1.0f; M = v; }
      }
    } else {
      uint32_t taken = 0;
      for (int j = 0; j < NROWS && taken < need; ++j) {
        if (keys[j] == T) {
          float v = mat_sim[mbase + j] / TEMP;
          if (v <= M) S += expf(v - M);
          else { S = S * expf(M - v) + 1.0f; M = v; }
          ++taken;
        }
      }
    }
    float lp = l_pos / TEMP, pv = posv / TEMP, pw = posw / TEMP;
    float L = 0.f;
    { float X = fmaxf(M, lp); L += X + logf(expf(lp - X) + S * expf(M - X)) - lp; }
    { float X = fmaxf(M, pv); L += X + logf(expf(pv - X) + S * expf(M - X)) - pv; }
    { float X = fmaxf(M, pw); L += X + logf(expf(pw - X) + S * expf(M - X)) - pw; }
    row_loss[i] = L;
  }
}

// ---------------------------------------------------------------- finalize loss
__global__ void finalize_loss(const float* __restrict__ row_loss,
                              float* __restrict__ out) {
  __shared__ float sm[4];
  int t = threadIdx.x;
  float v = row_loss[t];
  for (int o = 32; o; o >>= 1) v += __shfl_down(v, o, 64);
  if ((t & 63) == 0) sm[t >> 6] = v;
  __syncthreads();
  if (t == 0) out[0] = (sm[0] + sm[1] + sm[2] + sm[3]) * (1.0f / BATCH);
}

// -------------------------------- fallback cleanup: copy front rows afterwards
__global__ void copy_front(const float* __restrict__ src,
                           float* __restrict__ dst, int n4) {
  int idx = blockIdx.x * blockDim.x + threadIdx.x;
  int stride = gridDim.x * blockDim.x;
  for (int i = idx; i < n4; i += stride) {
    f32x4 v = *(const f32x4*)&src[(size_t)i * 4];
    float* d = &dst[(size_t)i * 4];
    d[0] = v[0]; d[1] = v[1]; d[2] = v[2]; d[3] = v[3];
  }
}

// --------------------------------------------- momentum update of touched rows
__global__ __launch_bounds__(256) void update_rows(
    const float* __restrict__ f, const float* __restrict__ features,
    const int* __restrict__ indexes, float* __restrict__ outF) {
  __shared__ float sred[16];
  const int i = blockIdx.x;
  const int row = indexes[i];
  for (int i2 = i + 1; i2 < BATCH; ++i2)
    if (indexes[i2] == row) return;          // last occurrence wins
  const int t = threadIdx.x;
  float ss = 0.f;
  for (int d = t; d < DIM; d += 256) {
    float u = 0.2f * features[(size_t)row * DIM + d] + 0.8f * f[(size_t)i * DIM + d];
    ss += u * u;
  }
  ss = block_sum(ss, sred);
  float nrm = fmaxf(sqrtf(ss), 1e-12f);
  for (int d = t; d < DIM; d += 256) {
    float u = 0.2f * features[(size_t)row * DIM + d] + 0.8f * f[(size_t)i * DIM + d];
    outF[(size_t)row * DIM + d] = u / nrm;
  }
}

// ------------------------------------------------------------------- launcher
extern "C" void kernel_launch(void* const* d_in, const int* in_sizes, int n_in,
                              void* d_out, int out_size, void* d_ws, size_t ws_size,
                              hipStream_t stream) {
  (void)in_sizes; (void)n_in; (void)out_size;
  const float* f        = (const float*)d_in[0];
  const float* f_nv     = (const float*)d_in[1];
  const float* features = (const float*)d_in[2];
  const int*   labels   = (const int*)d_in[3];
  const int*   indexes  = (const int*)d_in[4];
  float* out = (float*)d_out;

  // scratch: mat_sim (32 MB) + row_loss + packed A' (1 MB); prefer d_ws
  const size_t need = ((size_t)BATCH * NROWS + 256 + 262144) * sizeof(float);
  float* mat_sim;
  float* row_loss;
  uint32_t* Abf;
  int skip_rows;
  bool use_ws = (d_ws != nullptr) && (ws_size >= need);
  if (use_ws) {
    mat_sim = (float*)d_ws;
    row_loss = mat_sim + (size_t)BATCH * NROWS;
    Abf = (uint32_t*)(row_loss + 256);
    skip_rows = 0;
  } else {
    mat_sim = out + 4;
    row_loss = mat_sim + (size_t)BATCH * NROWS;
    Abf = (uint32_t*)(row_loss + 256);
    skip_rows = 4352;   // scratch occupies feature rows < 4352; fixed by copy_front
  }

  // kg1..kg3 = split(key(42), 3), partitionable threefry
  uint32_t c[6];
  { uint32_t a, b;
    tf2x32(0u, 42u, 0u, 0u, a, b); c[0] = a; c[1] = b;
    tf2x32(0u, 42u, 0u, 1u, a, b); c[2] = a; c[3] = b;
    tf2x32(0u, 42u, 0u, 2u, a, b); c[4] = a; c[5] = b; }

  cvtA<<<dim3(256), dim3(256), 0, stream>>>(f_nv, Abf);
  gemm_direct<<<dim3(NROWS / 32), dim3(256), 0, stream>>>(
      Abf, features, mat_sim, out + 1, skip_rows);
  sample_loss<<<dim3(BATCH), dim3(1024), 0, stream>>>(
      f, f_nv, features, labels, indexes, mat_sim, row_loss,
      c[0], c[1], c[2], c[3], c[4], c[5]);
  finalize_loss<<<dim3(1), dim3(256), 0, stream>>>(row_loss, out);
  if (!use_ws) {
    copy_front<<<dim3(2048), dim3(256), 0, stream>>>(
        features, out + 1, 4352 * DIM / 4);
  }
  update_rows<<<dim3(BATCH), dim3(256), 0, stream>>>(f, features, indexes, out + 1);
}

// Round 7
// 340.565 us; speedup vs baseline: 1.2797x; 1.2797x over previous
//
#include <hip/hip_runtime.h>
#include <stdint.h>

#define TEMP      0.07f
#define BATCH     256
#define NROWS     32768
#define DIM       2048
#define KNEG      8192

typedef __attribute__((ext_vector_type(8))) short bf16x8;
typedef __attribute__((ext_vector_type(4))) float f32x4;

// ---------------------------------------------------------------- threefry2x32
__host__ __device__ inline void tf2x32(uint32_t ka, uint32_t kb,
                                       uint32_t x0, uint32_t x1,
                                       uint32_t& o0, uint32_t& o1) {
  uint32_t ks2 = ka ^ kb ^ 0x1BD11BDAu;
#define TFR(r) { x0 += x1; x1 = (x1 << r) | (x1 >> (32 - r)); x1 ^= x0; }
  x0 += ka; x1 += kb;
  TFR(13) TFR(15) TFR(26) TFR(6)
  x0 += kb;  x1 += ks2 + 1u;
  TFR(17) TFR(29) TFR(16) TFR(24)
  x0 += ks2; x1 += ka + 2u;
  TFR(13) TFR(15) TFR(26) TFR(6)
  x0 += ka;  x1 += kb + 3u;
  TFR(17) TFR(29) TFR(16) TFR(24)
  x0 += kb;  x1 += ks2 + 4u;
  TFR(13) TFR(15) TFR(26) TFR(6)
  x0 += ks2; x1 += ka + 5u;
#undef TFR
  o0 = x0; o1 = x1;
}

// partitionable threefry (JAX >= 0.4.36): bits = out0 ^ out1, counter = (0, q)
__device__ inline uint32_t ubits_at(uint32_t ka, uint32_t kb, uint32_t q) {
  uint32_t a, b; tf2x32(ka, kb, 0u, q, a, b);
  return (a ^ b) >> 9;
}

// ---------------------------------------------------------------- block reduce
__device__ inline float block_sum(float v, float* sm) {
  __syncthreads();
  const int lane = threadIdx.x & 63;
  const int w = threadIdx.x >> 6;
  const int nw = blockDim.x >> 6;
  for (int o = 32; o; o >>= 1) v += __shfl_down(v, o, 64);
  if (lane == 0) sm[w] = v;
  __syncthreads();
  if (w == 0) {
    float x = (lane < nw) ? sm[lane] : 0.f;
    for (int o = 8; o; o >>= 1) x += __shfl_down(x, o, 64);
    if (lane == 0) sm[0] = x;
  }
  __syncthreads();
  return sm[0];
}

__device__ inline uint32_t pk2(float a, float b) {  // 2x fp32 -> packed bf16 (RNE)
  uint32_t ua = __float_as_uint(a), ub = __float_as_uint(b);
  ua = (ua + 0x7FFFu + ((ua >> 16) & 1u)) >> 16;
  ub = (ub + 0x7FFFu + ((ub >> 16) & 1u)) >> 16;
  return ua | (ub << 16);
}

// -------------------------- pack f_nv into bf16 MFMA A-fragment layout (1 MB)
// Fragment tile (mt,kt): 1 KB, lane l holds rows mt*16+(l&15), k kt*32+(l>>4)*8.
__global__ __launch_bounds__(256) void cvtA(const float* __restrict__ A,
                                            uint32_t* __restrict__ Abf) {
  const int t = threadIdx.x;
  const int w = blockIdx.x * 4 + (t >> 6);   // 1024 fragment tiles
  const int l = t & 63;
  const int mt = w >> 6, kt = w & 63;
  const float* src = &A[(size_t)(mt * 16 + (l & 15)) * DIM + kt * 32 + (l >> 4) * 8];
  float4 f0 = *(const float4*)src;
  float4 f1 = *(const float4*)(src + 4);
  *(uint4*)(Abf + (size_t)w * 256 + l * 4) =
      make_uint4(pk2(f0.x, f0.y), pk2(f0.z, f0.w), pk2(f1.x, f1.y), pk2(f1.z, f1.w));
}

// ------------------------------------------------------- async LDS staging DMA
__device__ inline void gll16(const float* g, float* l) {
  // HW writes lds_base + lane*16; global addr is per-lane.
  __builtin_amdgcn_global_load_lds(
      (const __attribute__((address_space(1))) uint32_t*)g,
      (__attribute__((address_space(3))) uint32_t*)l, 16, 0, 0);
}

// --------------------- m97-structure GEMM (128x128 tile) + fused outF copy
// B (features fp32) staged to 32KB LDS via global_load_lds each K-step,
// plain double __syncthreads per step (compiler manages all counters).
// A = packed bf16 fragments from L2 (1 MB). fp32->bf16 cvt at fragment read.
// Source-address XOR pre-swizzle (16B granules) kills LDS read conflicts.
#define NKS (DIM / 64)     // 32 K-steps of BK=64

__global__ __launch_bounds__(256, 3) void gemm_tile(
    const uint32_t* __restrict__ Abf,  // packed f_nv bf16 A-fragments
    const float* __restrict__ Bfeat,   // features [32768][2048]
    float* __restrict__ C,             // mat_sim [256][32768]
    float* __restrict__ outF,          // out+1 (new_features)
    int skip) {                        // copy only feature rows >= skip
  __shared__ float Bs[128 * 64];       // 32 KiB fp32 B-tile
  const int t = threadIdx.x;
  const int l = t & 63, w = t >> 6;
  const int bm = blockIdx.x & 1;       // adjacent blocks share the B-panel
  const int bn = blockIdx.x >> 1;
  const int wr = w >> 1, wc = w & 1;   // 2x2 wave grid, 64x64 out each
  const bool doCopy = (bm == 0);

  f32x4 acc[4][4] = {};

  for (int t0 = 0; t0 < NKS; ++t0) {
    const int k0 = t0 * 64;
    __syncthreads();                   // previous tile fully consumed
    // ---- stage B tile: 32 DMA insts, LDS linear, source pre-swizzled
#pragma unroll
    for (int i = 0; i < 8; ++i) {
      const int ii = w * 8 + i;            // 0..31, 1KB each (4 rows)
      const int r = 4 * ii + (l >> 4);     // tile row this lane feeds
      const int g = (l & 15) ^ ((r & 7) << 1);   // logical 16B granule
      gll16(&Bfeat[(size_t)(bn * 128 + r) * DIM + k0 + g * 4], &Bs[ii * 256]);
    }
    __syncthreads();                   // compiler drains vmcnt -> tile ready
    // ---- fused features->outF copy (L2-hot re-read, nontemporal store)
    if (doCopy) {
#pragma unroll
      for (int i = 0; i < 8; ++i) {
        const int G = i * 256 + t;         // 16B granule of the 32KB tile
        const int gr = bn * 128 + (G >> 4);
        const size_t off = (size_t)gr * DIM + k0 + (G & 15) * 4;
        f32x4 v = *(const f32x4*)&Bfeat[off];
        if (gr >= skip)
          __builtin_nontemporal_store(v, (f32x4*)&outF[off]);
      }
    }
    // ---- compute: 2 x (4 A-frag loads, 4 B-frag cvt, 16 MFMA)
#pragma unroll
    for (int kk = 0; kk < 2; ++kk) {
      bf16x8 af[4];
#pragma unroll
      for (int m = 0; m < 4; ++m)
        af[m] = *(const bf16x8*)(Abf +
            ((size_t)((bm * 8 + wr * 4 + m) * 64 + t0 * 2 + kk) * 64 + l) * 4);
      bf16x8 bfr[4];
#pragma unroll
      for (int n = 0; n < 4; ++n) {
        const int row = wc * 64 + n * 16 + (l & 15);
        const int e = (2 * (kk * 4 + (l >> 4))) ^ ((row & 7) << 1);
        const float* bp = &Bs[row * 64 + e * 4];
        f32x4 lo = *(const f32x4*)bp;
        f32x4 hi = *(const f32x4*)(bp + 4);
        uint32_t c0, c1, c2, c3;
        asm("v_cvt_pk_bf16_f32 %0, %1, %2" : "=v"(c0) : "v"(lo[0]), "v"(lo[1]));
        asm("v_cvt_pk_bf16_f32 %0, %1, %2" : "=v"(c1) : "v"(lo[2]), "v"(lo[3]));
        asm("v_cvt_pk_bf16_f32 %0, %1, %2" : "=v"(c2) : "v"(hi[0]), "v"(hi[1]));
        asm("v_cvt_pk_bf16_f32 %0, %1, %2" : "=v"(c3) : "v"(hi[2]), "v"(hi[3]));
        union { uint32_t u[4]; bf16x8 b; } cv;
        cv.u[0] = c0; cv.u[1] = c1; cv.u[2] = c2; cv.u[3] = c3;
        bfr[n] = cv.b;
      }
#pragma unroll
      for (int m = 0; m < 4; ++m)
#pragma unroll
        for (int n = 0; n < 4; ++n)
          acc[m][n] = __builtin_amdgcn_mfma_f32_16x16x32_bf16(
              af[m], bfr[n], acc[m][n], 0, 0, 0);
    }
  }

  // ---- epilogue: C write (coalesced 16-lane row segments)
#pragma unroll
  for (int m = 0; m < 4; ++m)
#pragma unroll
    for (int n = 0; n < 4; ++n) {
      const int row0 = bm * 128 + wr * 64 + m * 16 + (l >> 4) * 4;
      const int col = bn * 128 + wc * 64 + n * 16 + (l & 15);
#pragma unroll
      for (int r = 0; r < 4; ++r)
        C[(size_t)(row0 + r) * NROWS + col] = acc[m][n][r];
    }
}

// -------------------------------------------------- per-row sampling + CE loss
__global__ __launch_bounds__(1024) void sample_loss(
    const float* __restrict__ f, const float* __restrict__ f_nv,
    const float* __restrict__ features, const int* __restrict__ labels,
    const int* __restrict__ indexes, const float* __restrict__ mat_sim,
    float* __restrict__ row_loss,
    uint32_t k1a, uint32_t k1b, uint32_t k2a, uint32_t k2b,
    uint32_t k3a, uint32_t k3b) {
  __shared__ uint32_t keys[NROWS];      // 128 KiB sortable uniform bits
  __shared__ uint32_t hist4[4][256];    // privatized histograms
  __shared__ uint32_t hist[256];
  __shared__ unsigned long long am1, am2;
  __shared__ int tie_j[128];
  __shared__ int tie_cnt;
  __shared__ float sred[16];
  __shared__ float swm[16], sws[16];
  __shared__ uint32_t bc_prefix, bc_rem;
  __shared__ int blab_s;

  const int t = threadIdx.x;
  const int i = blockIdx.x;
  const size_t mbase = (size_t)i * NROWS;

  if (t == 0) {
    blab_s = labels[indexes[i]];
    am1 = 0ull; am2 = 0ull; tie_cnt = 0;
  }
  ((uint32_t*)hist4)[t] = 0u;           // pass-0 histogram built during phase 1
  __syncthreads();
  const int blab = blab_s;
  const int hsel = t >> 8;

  // phase 1: keys for g3 (positives -> 0), argmax of g1/g2 over positives,
  // fused radix pass-0 histogram (bucket = key >> 15)
#pragma unroll 2
  for (int s = 0; s < NROWS / 1024; ++s) {
    int j = t + 1024 * s;
    uint32_t q = (uint32_t)i * NROWS + (uint32_t)j;
    int lab = labels[j];
    uint32_t key;
    if (lab == blab) {
      key = 0u;
      unsigned long long lo = (unsigned long long)(uint32_t)(NROWS - 1 - j);
      uint32_t u1 = ubits_at(k1a, k1b, q);
      uint32_t u2 = ubits_at(k2a, k2b, q);
      atomicMax(&am1, ((unsigned long long)u1 << 32) | lo);
      atomicMax(&am2, ((unsigned long long)u2 << 32) | lo);
    } else {
      key = ubits_at(k3a, k3b, q);
    }
    keys[j] = key;
    atomicAdd(&hist4[hsel][key >> 15], 1u);
  }
  __syncthreads();

  const int jw = NROWS - 1 - (int)(unsigned)(am1 & 0xFFFFFFFFull);
  const int jp = NROWS - 1 - (int)(unsigned)(am2 & 0xFFFFFFFFull);

  const int bank = indexes[i];
  float d1 = 0.f, d2 = 0.f, d3 = 0.f;
  for (int d = t; d < DIM; d += 1024) {
    float fnv = f_nv[(size_t)i * DIM + d];
    d1 += fnv * features[(size_t)bank * DIM + d];
    d2 += f[(size_t)i * DIM + d] * features[(size_t)jw * DIM + d];
    d3 += fnv * features[(size_t)jp * DIM + d];
  }
  const float l_pos = block_sum(d1, sred);
  const float posw  = block_sum(d2, sred);
  const float posv  = block_sum(d3, sred);

  // 3-pass radix select (pass 0 pre-built): K-th largest of 23-bit keys
  uint32_t prefix = 0, remaining = KNEG;
  const int shifts[3] = {15, 7, 0};
  const int nbits[3]  = {8, 8, 7};
  for (int p = 0; p < 3; ++p) {
    const int sh = shifts[p];
    const int nb = 1 << nbits[p];
    if (p) {
      ((uint32_t*)hist4)[t] = 0u;
      __syncthreads();
      for (int s = 0; s < NROWS / 1024; ++s) {
        int j = t + 1024 * s;
        uint32_t k = keys[j];
        if ((k >> (sh + nbits[p])) == prefix)
          atomicAdd(&hist4[hsel][(k >> sh) & (uint32_t)(nb - 1)], 1u);
      }
    }
    __syncthreads();
    if (t < nb) hist[t] = hist4[0][t] + hist4[1][t] + hist4[2][t] + hist4[3][t];
    __syncthreads();
    if (t == 0) {
      uint32_t c = 0; int b = nb - 1;
      for (;; --b) {
        c += hist[b];
        if (c >= remaining || b == 0) break;
      }
      bc_prefix = (prefix << nbits[p]) | (uint32_t)b;
      bc_rem = remaining - (c - hist[b]);
    }
    __syncthreads();
    prefix = bc_prefix; remaining = bc_rem;
  }
  const uint32_t T = prefix;
  const uint32_t need = remaining;

  float m = -INFINITY, ssum = 0.f;
  for (int s = 0; s < NROWS / 1024; ++s) {
    int j = t + 1024 * s;
    uint32_t k = keys[j];
    if (k > T) {
      float v = mat_sim[mbase + j] / TEMP;
      if (v <= m) ssum += expf(v - m);
      else { ssum = ssum * expf(m - v) + 1.0f; m = v; }
    } else if (k == T) {
      int p = atomicAdd(&tie_cnt, 1);
      if (p < 128) tie_j[p] = j;
    }
  }
  for (int o = 32; o; o >>= 1) {
    float m2 = __shfl_down(m, o, 64);
    float s2 = __shfl_down(ssum, o, 64);
    if (m2 > m) { ssum = ssum * expf(m - m2) + s2; m = m2; }
    else if (m2 != -INFINITY) ssum += s2 * expf(m2 - m);
  }
  if ((t & 63) == 0) { swm[t >> 6] = m; sws[t >> 6] = ssum; }
  __syncthreads();
  if (t < 64) {
    float mm = (t < 16) ? swm[t] : -INFINITY;
    float ss = (t < 16) ? sws[t] : 0.f;
    for (int o = 8; o; o >>= 1) {
      float m2 = __shfl_down(mm, o, 64);
      float s2 = __shfl_down(ss, o, 64);
      if (m2 > mm) { ss = ss * expf(mm - m2) + s2; mm = m2; }
      else if (m2 != -INFINITY) ss += s2 * expf(m2 - mm);
    }
    if (t == 0) { swm[0] = mm; sws[0] = ss; }
  }
  __syncthreads();

  if (t == 0) {
    float M = swm[0], S = sws[0];
    int tc = tie_cnt;
    if (tc <= 128) {
      for (int a2 = 1; a2 < tc; ++a2) {
        int v = tie_j[a2]; int b2 = a2 - 1;
        while (b2 >= 0 && tie_j[b2] > v) { tie_j[b2 + 1] = tie_j[b2]; --b2; }
        tie_j[b2 + 1] = v;
      }
      for (uint32_t r = 0; r < need; ++r) {
        float v = mat_sim[mbase + tie_j[r]] / TEMP;
        if (v <= M) S += expf(v - M);
        else { S = S * expf(M - v) + 1.0f; M = v; }
      }
    } else {
      uint32_t taken = 0;
      for (int j = 0; j < NROWS && taken < need; ++j) {
        if (keys[j] == T) {
          float v = mat_sim[mbase + j] / TEMP;
          if (v <= M) S += expf(v - M);
          else { S = S * expf(M - v) + 1.0f; M = v; }
          ++taken;
        }
      }
    }
    float lp = l_pos / TEMP, pv = posv / TEMP, pw = posw / TEMP;
    float L = 0.f;
    { float X = fmaxf(M, lp); L += X + logf(expf(lp - X) + S * expf(M - X)) - lp; }
    { float X = fmaxf(M, pv); L += X + logf(expf(pv - X) + S * expf(M - X)) - pv; }
    { float X = fmaxf(M, pw); L += X + logf(expf(pw - X) + S * expf(M - X)) - pw; }
    row_loss[i] = L;
  }
}

// ---------------------------------------------------------------- finalize loss
__global__ void finalize_loss(const float* __restrict__ row_loss,
                              float* __restrict__ out) {
  __shared__ float sm[4];
  int t = threadIdx.x;
  float v = row_loss[t];
  for (int o = 32; o; o >>= 1) v += __shfl_down(v, o, 64);
  if ((t & 63) == 0) sm[t >> 6] = v;
  __syncthreads();
  if (t == 0) out[0] = (sm[0] + sm[1] + sm[2] + sm[3]) * (1.0f / BATCH);
}

// -------------------------------- fallback cleanup: copy front rows afterwards
__global__ void copy_front(const float* __restrict__ src,
                           float* __restrict__ dst, int n4) {
  int idx = blockIdx.x * blockDim.x + threadIdx.x;
  int stride = gridDim.x * blockDim.x;
  for (int i = idx; i < n4; i += stride) {
    f32x4 v = *(const f32x4*)&src[(size_t)i * 4];
    float* d = &dst[(size_t)i * 4];
    d[0] = v[0]; d[1] = v[1]; d[2] = v[2]; d[3] = v[3];
  }
}

// --------------------------------------------- momentum update of touched rows
__global__ __launch_bounds__(256) void update_rows(
    const float* __restrict__ f, const float* __restrict__ features,
    const int* __restrict__ indexes, float* __restrict__ outF) {
  __shared__ float sred[16];
  const int i = blockIdx.x;
  const int row = indexes[i];
  for (int i2 = i + 1; i2 < BATCH; ++i2)
    if (indexes[i2] == row) return;          // last occurrence wins
  const int t = threadIdx.x;
  float ss = 0.f;
  for (int d = t; d < DIM; d += 256) {
    float u = 0.2f * features[(size_t)row * DIM + d] + 0.8f * f[(size_t)i * DIM + d];
    ss += u * u;
  }
  ss = block_sum(ss, sred);
  float nrm = fmaxf(sqrtf(ss), 1e-12f);
  for (int d = t; d < DIM; d += 256) {
    float u = 0.2f * features[(size_t)row * DIM + d] + 0.8f * f[(size_t)i * DIM + d];
    outF[(size_t)row * DIM + d] = u / nrm;
  }
}

// ------------------------------------------------------------------- launcher
extern "C" void kernel_launch(void* const* d_in, const int* in_sizes, int n_in,
                              void* d_out, int out_size, void* d_ws, size_t ws_size,
                              hipStream_t stream) {
  (void)in_sizes; (void)n_in; (void)out_size;
  const float* f        = (const float*)d_in[0];
  const float* f_nv     = (const float*)d_in[1];
  const float* features = (const float*)d_in[2];
  const int*   labels   = (const int*)d_in[3];
  const int*   indexes  = (const int*)d_in[4];
  float* out = (float*)d_out;

  // scratch: mat_sim (32 MB) + row_loss + packed A' (1 MB); prefer d_ws
  const size_t need = ((size_t)BATCH * NROWS + 256 + 262144) * sizeof(float);
  float* mat_sim;
  float* row_loss;
  uint32_t* Abf;
  int skip_rows;
  bool use_ws = (d_ws != nullptr) && (ws_size >= need);
  if (use_ws) {
    mat_sim = (float*)d_ws;
    row_loss = mat_sim + (size_t)BATCH * NROWS;
    Abf = (uint32_t*)(row_loss + 256);
    skip_rows = 0;
  } else {
    mat_sim = out + 4;
    row_loss = mat_sim + (size_t)BATCH * NROWS;
    Abf = (uint32_t*)(row_loss + 256);
    skip_rows = 4352;   // scratch occupies feature rows < 4352; fixed by copy_front
  }

  // kg1..kg3 = split(key(42), 3), partitionable threefry
  uint32_t c[6];
  { uint32_t a, b;
    tf2x32(0u, 42u, 0u, 0u, a, b); c[0] = a; c[1] = b;
    tf2x32(0u, 42u, 0u, 1u, a, b); c[2] = a; c[3] = b;
    tf2x32(0u, 42u, 0u, 2u, a, b); c[4] = a; c[5] = b; }

  cvtA<<<dim3(256), dim3(256), 0, stream>>>(f_nv, Abf);
  gemm_tile<<<dim3(2 * NROWS / 128), dim3(256), 0, stream>>>(
      Abf, features, mat_sim, out + 1, skip_rows);
  sample_loss<<<dim3(BATCH), dim3(1024), 0, stream>>>(
      f, f_nv, features, labels, indexes, mat_sim, row_loss,
      c[0], c[1], c[2], c[3], c[4], c[5]);
  finalize_loss<<<dim3(1), dim3(256), 0, stream>>>(row_loss, out);
  if (!use_ws) {
    copy_front<<<dim3(2048), dim3(256), 0, stream>>>(
        features, out + 1, 4352 * DIM / 4);
  }
  update_rows<<<dim3(BATCH), dim3(256), 0, stream>>>(f, features, indexes, out + 1);
}

// Round 8
// 284.458 us; speedup vs baseline: 1.5322x; 1.1972x over previous
//
#include <hip/hip_runtime.h>
#include <stdint.h>

#define TEMP      0.07f
#define BATCH     256
#define NROWS     32768
#define DIM       2048
#define KNEG      8192

typedef __attribute__((ext_vector_type(8))) short bf16x8;
typedef __attribute__((ext_vector_type(4))) float f32x4;

// ---------------------------------------------------------------- threefry2x32
__host__ __device__ inline void tf2x32(uint32_t ka, uint32_t kb,
                                       uint32_t x0, uint32_t x1,
                                       uint32_t& o0, uint32_t& o1) {
  uint32_t ks2 = ka ^ kb ^ 0x1BD11BDAu;
#define TFR(r) { x0 += x1; x1 = (x1 << r) | (x1 >> (32 - r)); x1 ^= x0; }
  x0 += ka; x1 += kb;
  TFR(13) TFR(15) TFR(26) TFR(6)
  x0 += kb;  x1 += ks2 + 1u;
  TFR(17) TFR(29) TFR(16) TFR(24)
  x0 += ks2; x1 += ka + 2u;
  TFR(13) TFR(15) TFR(26) TFR(6)
  x0 += ka;  x1 += kb + 3u;
  TFR(17) TFR(29) TFR(16) TFR(24)
  x0 += kb;  x1 += ks2 + 4u;
  TFR(13) TFR(15) TFR(26) TFR(6)
  x0 += ks2; x1 += ka + 5u;
#undef TFR
  o0 = x0; o1 = x1;
}

// partitionable threefry (JAX >= 0.4.36): bits = out0 ^ out1, counter = (0, q)
__device__ inline uint32_t ubits_at(uint32_t ka, uint32_t kb, uint32_t q) {
  uint32_t a, b; tf2x32(ka, kb, 0u, q, a, b);
  return (a ^ b) >> 9;
}

// ---------------------------------------------------------------- block reduce
__device__ inline float block_sum(float v, float* sm) {
  __syncthreads();
  const int lane = threadIdx.x & 63;
  const int w = threadIdx.x >> 6;
  const int nw = blockDim.x >> 6;
  for (int o = 32; o; o >>= 1) v += __shfl_down(v, o, 64);
  if (lane == 0) sm[w] = v;
  __syncthreads();
  if (w == 0) {
    float x = (lane < nw) ? sm[lane] : 0.f;
    for (int o = 8; o; o >>= 1) x += __shfl_down(x, o, 64);
    if (lane == 0) sm[0] = x;
  }
  __syncthreads();
  return sm[0];
}

__device__ inline uint32_t pk2(float a, float b) {  // 2x fp32 -> packed bf16 (RNE)
  uint32_t ua = __float_as_uint(a), ub = __float_as_uint(b);
  ua = (ua + 0x7FFFu + ((ua >> 16) & 1u)) >> 16;
  ub = (ub + 0x7FFFu + ((ub >> 16) & 1u)) >> 16;
  return ua | (ub << 16);
}

// -------------------------- pack f_nv into bf16 MFMA A-fragment layout (1 MB)
// Fragment tile (mt,kt): 1 KB, lane l holds rows mt*16+(l&15), k kt*32+(l>>4)*8.
__global__ __launch_bounds__(256) void cvtA(const float* __restrict__ A,
                                            uint32_t* __restrict__ Abf) {
  const int t = threadIdx.x;
  const int w = blockIdx.x * 4 + (t >> 6);   // 1024 fragment tiles
  const int l = t & 63;
  const int mt = w >> 6, kt = w & 63;
  const float* src = &A[(size_t)(mt * 16 + (l & 15)) * DIM + kt * 32 + (l >> 4) * 8];
  float4 f0 = *(const float4*)src;
  float4 f1 = *(const float4*)(src + 4);
  *(uint4*)(Abf + (size_t)w * 256 + l * 4) =
      make_uint4(pk2(f0.x, f0.y), pk2(f0.z, f0.w), pk2(f1.x, f1.y), pk2(f1.z, f1.w));
}

// ------------------------------------------------------- async LDS staging DMA
__device__ inline void gll16(const float* g, float* l) {
  __builtin_amdgcn_global_load_lds(
      (const __attribute__((address_space(1))) uint32_t*)g,
      (__attribute__((address_space(3))) uint32_t*)l, 16, 0, 0);
}

// ------------------- heterogeneous kernel: streaming copy + GEMM co-scheduled
// 512 groups x 3 blocks: roles 0,1 = copy 32 feature rows each (full-row
// sequential stream, DRAM-optimal, primes L3); role 2 = GEMM block for the
// same 64 feature rows (BM=256 x BN=64, BK=64; B via gll->LDS now L3-hot,
// A from packed bf16 fragments in L2). Copy blocks keep HBM saturated while
// GEMM blocks sit in latency; 4-6 blocks/CU co-resident.
__global__ __launch_bounds__(256, 4) void mega(
    const uint32_t* __restrict__ Abf,  // packed f_nv bf16 A-fragments
    const float* __restrict__ Bfeat,   // features [32768][2048]
    float* __restrict__ C,             // mat_sim [256][32768]
    float* __restrict__ outF,          // out+1 (new_features)
    int skip) {                        // copy only feature rows >= skip
  __shared__ float Bs[64 * 64];        // 16 KiB fp32 B-tile (role 2 only)
  const int role = blockIdx.x % 3;
  const int g = blockIdx.x / 3;        // 512 groups, rows/cols g*64..g*64+63
  const int t = threadIdx.x;

  if (role < 2) {
    // ---------------- streaming copy of 32 full rows (256 KB) ----------------
    const int r0 = g * 64 + role * 32;
    const float* src = Bfeat + (size_t)r0 * DIM;
    float* dst = outF + (size_t)r0 * DIM;
    const int total4 = 32 * DIM / 4;           // 16384 f32x4
#pragma unroll 4
    for (int i = t; i < total4; i += 256) {
      const int gr = r0 + (i >> 9);            // i*4/DIM
      f32x4 v = *(const f32x4*)(src + (size_t)i * 4);
      if (gr >= skip)
        __builtin_nontemporal_store(v, (f32x4*)(dst + (size_t)i * 4));
    }
    return;
  }

  // ------------------------------- GEMM block ------------------------------
  const int l = t & 63, w = t >> 6;
  f32x4 acc[4][4] = {};

  for (int t0 = 0; t0 < DIM / 64; ++t0) {
    __syncthreads();                       // previous tile consumed
    // stage B tile 64x64 fp32: 4 gll per wave, LDS linear, src granule-XOR'd
#pragma unroll
    for (int i = 0; i < 4; ++i) {
      const int ii = w * 4 + i;            // 16 x 1KB
      const int r = 4 * ii + (l >> 4);     // tile row
      const int gs = (l & 15) ^ (r & 7);   // global granule for LDS slot l&15
      gll16(&Bfeat[(size_t)(g * 64 + r) * DIM + t0 * 64 + gs * 4],
            &Bs[ii * 256]);
    }
    __syncthreads();                       // tile ready (compiler drains)
#pragma unroll
    for (int kk = 0; kk < 2; ++kk) {
      bf16x8 af[4];
#pragma unroll
      for (int m = 0; m < 4; ++m)
        af[m] = *(const bf16x8*)(Abf +
            ((size_t)((w * 4 + m) * 64 + t0 * 2 + kk) * 64 + l) * 4);
      bf16x8 bfr[4];
#pragma unroll
      for (int n = 0; n < 4; ++n) {
        const int row = n * 16 + (l & 15);
        const int b2 = 2 * (kk * 4 + (l >> 4));
        const int s = row & 7;
        f32x4 lo = *(const f32x4*)&Bs[row * 64 + (b2 ^ s) * 4];
        f32x4 hi = *(const f32x4*)&Bs[row * 64 + ((b2 + 1) ^ s) * 4];
        uint32_t c0, c1, c2, c3;
        asm("v_cvt_pk_bf16_f32 %0, %1, %2" : "=v"(c0) : "v"(lo[0]), "v"(lo[1]));
        asm("v_cvt_pk_bf16_f32 %0, %1, %2" : "=v"(c1) : "v"(lo[2]), "v"(lo[3]));
        asm("v_cvt_pk_bf16_f32 %0, %1, %2" : "=v"(c2) : "v"(hi[0]), "v"(hi[1]));
        asm("v_cvt_pk_bf16_f32 %0, %1, %2" : "=v"(c3) : "v"(hi[2]), "v"(hi[3]));
        union { uint32_t u[4]; bf16x8 b; } cv;
        cv.u[0] = c0; cv.u[1] = c1; cv.u[2] = c2; cv.u[3] = c3;
        bfr[n] = cv.b;
      }
#pragma unroll
      for (int m = 0; m < 4; ++m)
#pragma unroll
        for (int n = 0; n < 4; ++n)
          acc[m][n] = __builtin_amdgcn_mfma_f32_16x16x32_bf16(
              af[m], bfr[n], acc[m][n], 0, 0, 0);
    }
  }

  // epilogue: C write
#pragma unroll
  for (int m = 0; m < 4; ++m)
#pragma unroll
    for (int n = 0; n < 4; ++n) {
      const int row0 = w * 64 + m * 16 + (l >> 4) * 4;
      const int col = g * 64 + n * 16 + (l & 15);
#pragma unroll
      for (int r = 0; r < 4; ++r)
        C[(size_t)(row0 + r) * NROWS + col] = acc[m][n][r];
    }
}

// -------------------------------------------------- per-row sampling + CE loss
__global__ __launch_bounds__(1024) void sample_loss(
    const float* __restrict__ f, const float* __restrict__ f_nv,
    const float* __restrict__ features, const int* __restrict__ labels,
    const int* __restrict__ indexes, const float* __restrict__ mat_sim,
    float* __restrict__ row_loss,
    uint32_t k1a, uint32_t k1b, uint32_t k2a, uint32_t k2b,
    uint32_t k3a, uint32_t k3b) {
  __shared__ uint32_t keys[NROWS];      // 128 KiB sortable uniform bits
  __shared__ uint32_t hist4[4][256];    // privatized histograms
  __shared__ uint32_t hist[256];
  __shared__ unsigned long long am1, am2;
  __shared__ int tie_j[128];
  __shared__ int tie_cnt;
  __shared__ float sred[16];
  __shared__ float swm[16], sws[16];
  __shared__ uint32_t bc_prefix, bc_rem;
  __shared__ int blab_s;

  const int t = threadIdx.x;
  const int i = blockIdx.x;
  const size_t mbase = (size_t)i * NROWS;

  if (t == 0) {
    blab_s = labels[indexes[i]];
    am1 = 0ull; am2 = 0ull; tie_cnt = 0;
  }
  ((uint32_t*)hist4)[t] = 0u;           // pass-0 histogram built during phase 1
  __syncthreads();
  const int blab = blab_s;
  const int hsel = t >> 8;

#pragma unroll 2
  for (int s = 0; s < NROWS / 1024; ++s) {
    int j = t + 1024 * s;
    uint32_t q = (uint32_t)i * NROWS + (uint32_t)j;
    int lab = labels[j];
    uint32_t key;
    if (lab == blab) {
      key = 0u;
      unsigned long long lo = (unsigned long long)(uint32_t)(NROWS - 1 - j);
      uint32_t u1 = ubits_at(k1a, k1b, q);
      uint32_t u2 = ubits_at(k2a, k2b, q);
      atomicMax(&am1, ((unsigned long long)u1 << 32) | lo);
      atomicMax(&am2, ((unsigned long long)u2 << 32) | lo);
    } else {
      key = ubits_at(k3a, k3b, q);
    }
    keys[j] = key;
    atomicAdd(&hist4[hsel][key >> 15], 1u);
  }
  __syncthreads();

  const int jw = NROWS - 1 - (int)(unsigned)(am1 & 0xFFFFFFFFull);
  const int jp = NROWS - 1 - (int)(unsigned)(am2 & 0xFFFFFFFFull);

  const int bank = indexes[i];
  float d1 = 0.f, d2 = 0.f, d3 = 0.f;
  for (int d = t; d < DIM; d += 1024) {
    float fnv = f_nv[(size_t)i * DIM + d];
    d1 += fnv * features[(size_t)bank * DIM + d];
    d2 += f[(size_t)i * DIM + d] * features[(size_t)jw * DIM + d];
    d3 += fnv * features[(size_t)jp * DIM + d];
  }
  const float l_pos = block_sum(d1, sred);
  const float posw  = block_sum(d2, sred);
  const float posv  = block_sum(d3, sred);

  uint32_t prefix = 0, remaining = KNEG;
  const int shifts[3] = {15, 7, 0};
  const int nbits[3]  = {8, 8, 7};
  for (int p = 0; p < 3; ++p) {
    const int sh = shifts[p];
    const int nb = 1 << nbits[p];
    if (p) {
      ((uint32_t*)hist4)[t] = 0u;
      __syncthreads();
      for (int s = 0; s < NROWS / 1024; ++s) {
        int j = t + 1024 * s;
        uint32_t k = keys[j];
        if ((k >> (sh + nbits[p])) == prefix)
          atomicAdd(&hist4[hsel][(k >> sh) & (uint32_t)(nb - 1)], 1u);
      }
    }
    __syncthreads();
    if (t < nb) hist[t] = hist4[0][t] + hist4[1][t] + hist4[2][t] + hist4[3][t];
    __syncthreads();
    if (t == 0) {
      uint32_t c = 0; int b = nb - 1;
      for (;; --b) {
        c += hist[b];
        if (c >= remaining || b == 0) break;
      }
      bc_prefix = (prefix << nbits[p]) | (uint32_t)b;
      bc_rem = remaining - (c - hist[b]);
    }
    __syncthreads();
    prefix = bc_prefix; remaining = bc_rem;
  }
  const uint32_t T = prefix;
  const uint32_t need = remaining;

  float m = -INFINITY, ssum = 0.f;
  for (int s = 0; s < NROWS / 1024; ++s) {
    int j = t + 1024 * s;
    uint32_t k = keys[j];
    if (k > T) {
      float v = mat_sim[mbase + j] / TEMP;
      if (v <= m) ssum += expf(v - m);
      else { ssum = ssum * expf(m - v) + 1.0f; m = v; }
    } else if (k == T) {
      int p = atomicAdd(&tie_cnt, 1);
      if (p < 128) tie_j[p] = j;
    }
  }
  for (int o = 32; o; o >>= 1) {
    float m2 = __shfl_down(m, o, 64);
    float s2 = __shfl_down(ssum, o, 64);
    if (m2 > m) { ssum = ssum * expf(m - m2) + s2; m = m2; }
    else if (m2 != -INFINITY) ssum += s2 * expf(m2 - m);
  }
  if ((t & 63) == 0) { swm[t >> 6] = m; sws[t >> 6] = ssum; }
  __syncthreads();
  if (t < 64) {
    float mm = (t < 16) ? swm[t] : -INFINITY;
    float ss = (t < 16) ? sws[t] : 0.f;
    for (int o = 8; o; o >>= 1) {
      float m2 = __shfl_down(mm, o, 64);
      float s2 = __shfl_down(ss, o, 64);
      if (m2 > mm) { ss = ss * expf(mm - m2) + s2; mm = m2; }
      else if (m2 != -INFINITY) ss += s2 * expf(m2 - mm);
    }
    if (t == 0) { swm[0] = mm; sws[0] = ss; }
  }
  __syncthreads();

  if (t == 0) {
    float M = swm[0], S = sws[0];
    int tc = tie_cnt;
    if (tc <= 128) {
      for (int a2 = 1; a2 < tc; ++a2) {
        int v = tie_j[a2]; int b2 = a2 - 1;
        while (b2 >= 0 && tie_j[b2] > v) { tie_j[b2 + 1] = tie_j[b2]; --b2; }
        tie_j[b2 + 1] = v;
      }
      for (uint32_t r = 0; r < need; ++r) {
        float v = mat_sim[mbase + tie_j[r]] / TEMP;
        if (v <= M) S += expf(v - M);
        else { S = S * expf(M - v) + 1.0f; M = v; }
      }
    } else {
      uint32_t taken = 0;
      for (int j = 0; j < NROWS && taken < need; ++j) {
        if (keys[j] == T) {
          float v = mat_sim[mbase + j] / TEMP;
          if (v <= M) S += expf(v - M);
          else { S = S * expf(M - v) + 1.0f; M = v; }
          ++taken;
        }
      }
    }
    float lp = l_pos / TEMP, pv = posv / TEMP, pw = posw / TEMP;
    float L = 0.f;
    { float X = fmaxf(M, lp); L += X + logf(expf(lp - X) + S * expf(M - X)) - lp; }
    { float X = fmaxf(M, pv); L += X + logf(expf(pv - X) + S * expf(M - X)) - pv; }
    { float X = fmaxf(M, pw); L += X + logf(expf(pw - X) + S * expf(M - X)) - pw; }
    row_loss[i] = L;
  }
}

// ---------------------------------------------------------------- finalize loss
__global__ void finalize_loss(const float* __restrict__ row_loss,
                              float* __restrict__ out) {
  __shared__ float sm[4];
  int t = threadIdx.x;
  float v = row_loss[t];
  for (int o = 32; o; o >>= 1) v += __shfl_down(v, o, 64);
  if ((t & 63) == 0) sm[t >> 6] = v;
  __syncthreads();
  if (t == 0) out[0] = (sm[0] + sm[1] + sm[2] + sm[3]) * (1.0f / BATCH);
}

// -------------------------------- fallback cleanup: copy front rows afterwards
__global__ void copy_front(const float* __restrict__ src,
                           float* __restrict__ dst, int n4) {
  int idx = blockIdx.x * blockDim.x + threadIdx.x;
  int stride = gridDim.x * blockDim.x;
  for (int i = idx; i < n4; i += stride) {
    f32x4 v = *(const f32x4*)&src[(size_t)i * 4];
    float* d = &dst[(size_t)i * 4];
    d[0] = v[0]; d[1] = v[1]; d[2] = v[2]; d[3] = v[3];
  }
}

// --------------------------------------------- momentum update of touched rows
__global__ __launch_bounds__(256) void update_rows(
    const float* __restrict__ f, const float* __restrict__ features,
    const int* __restrict__ indexes, float* __restrict__ outF) {
  __shared__ float sred[16];
  const int i = blockIdx.x;
  const int row = indexes[i];
  for (int i2 = i + 1; i2 < BATCH; ++i2)
    if (indexes[i2] == row) return;          // last occurrence wins
  const int t = threadIdx.x;
  float ss = 0.f;
  for (int d = t; d < DIM; d += 256) {
    float u = 0.2f * features[(size_t)row * DIM + d] + 0.8f * f[(size_t)i * DIM + d];
    ss += u * u;
  }
  ss = block_sum(ss, sred);
  float nrm = fmaxf(sqrtf(ss), 1e-12f);
  for (int d = t; d < DIM; d += 256) {
    float u = 0.2f * features[(size_t)row * DIM + d] + 0.8f * f[(size_t)i * DIM + d];
    outF[(size_t)row * DIM + d] = u / nrm;
  }
}

// ------------------------------------------------------------------- launcher
extern "C" void kernel_launch(void* const* d_in, const int* in_sizes, int n_in,
                              void* d_out, int out_size, void* d_ws, size_t ws_size,
                              hipStream_t stream) {
  (void)in_sizes; (void)n_in; (void)out_size;
  const float* f        = (const float*)d_in[0];
  const float* f_nv     = (const float*)d_in[1];
  const float* features = (const float*)d_in[2];
  const int*   labels   = (const int*)d_in[3];
  const int*   indexes  = (const int*)d_in[4];
  float* out = (float*)d_out;

  // scratch: mat_sim (32 MB) + row_loss + packed A' (1 MB); prefer d_ws
  const size_t need = ((size_t)BATCH * NROWS + 256 + 262144) * sizeof(float);
  float* mat_sim;
  float* row_loss;
  uint32_t* Abf;
  int skip_rows;
  bool use_ws = (d_ws != nullptr) && (ws_size >= need);
  if (use_ws) {
    mat_sim = (float*)d_ws;
    row_loss = mat_sim + (size_t)BATCH * NROWS;
    Abf = (uint32_t*)(row_loss + 256);
    skip_rows = 0;
  } else {
    mat_sim = out + 4;
    row_loss = mat_sim + (size_t)BATCH * NROWS;
    Abf = (uint32_t*)(row_loss + 256);
    skip_rows = 4352;   // scratch occupies feature rows < 4352; fixed by copy_front
  }

  // kg1..kg3 = split(key(42), 3), partitionable threefry
  uint32_t c[6];
  { uint32_t a, b;
    tf2x32(0u, 42u, 0u, 0u, a, b); c[0] = a; c[1] = b;
    tf2x32(0u, 42u, 0u, 1u, a, b); c[2] = a; c[3] = b;
    tf2x32(0u, 42u, 0u, 2u, a, b); c[4] = a; c[5] = b; }

  cvtA<<<dim3(256), dim3(256), 0, stream>>>(f_nv, Abf);
  mega<<<dim3(3 * NROWS / 64), dim3(256), 0, stream>>>(
      Abf, features, mat_sim, out + 1, skip_rows);
  sample_loss<<<dim3(BATCH), dim3(1024), 0, stream>>>(
      f, f_nv, features, labels, indexes, mat_sim, row_loss,
      c[0], c[1], c[2], c[3], c[4], c[5]);
  finalize_loss<<<dim3(1), dim3(256), 0, stream>>>(row_loss, out);
  if (!use_ws) {
    copy_front<<<dim3(2048), dim3(256), 0, stream>>>(
        features, out + 1, 4352 * DIM / 4);
  }
  update_rows<<<dim3(BATCH), dim3(256), 0, stream>>>(f, features, indexes, out + 1);
}